// Round 2
// baseline (5412.561 us; speedup 1.0000x reference)
//
#include <hip/hip_runtime.h>
#include <hip/hip_bf16.h>
#include <hip/hip_cooperative_groups.h>

namespace cg = cooperative_groups;

// Persistent cooperative LSTM: 256 blocks (1/CU) x 512 threads, 64 steps inside
// one kernel with grid.sync() between steps.
//  - Bs: block's 64-col gate-interleaved slice of [W;U]^T in LDS (64x1032 bf16,
//        +8 pad -> 16B-aligned rows, bank-even b128 frag reads). Loaded once.
//  - c state in registers (4 per thread, fixed (row,h) across steps).
//  - h ping-pong in ws (Hbuf[2]) -> one grid.sync per step, no r/w race.
//  - A (x_t | h) staged per 64-k chunk via global_load_lds width-16 into two
//    unpadded [128][32] sub-blocks (lane-contiguous dest; bank-even reads).

typedef __attribute__((ext_vector_type(8))) short bfrag8;
typedef __attribute__((ext_vector_type(4))) float facc4;

#define MFMA_B16(a, b, c) __builtin_amdgcn_mfma_f32_16x16x32_bf16(a, b, c, 0, 0, 0)

__device__ __forceinline__ unsigned short f2bf(float f) {
  unsigned int u = __float_as_uint(f);
  u += 0x7FFFu + ((u >> 16) & 1u);          // RNE
  return (unsigned short)(u >> 16);
}
__device__ __forceinline__ float sigm(float x)  { return 1.0f / (1.0f + __expf(-x)); }
__device__ __forceinline__ float tanh_(float x) { return 1.0f - 2.0f / (__expf(2.0f * x) + 1.0f); }

__device__ __forceinline__ void gl2lds16(const void* g, void* l) {
  __builtin_amdgcn_global_load_lds(
      (const __attribute__((address_space(1))) unsigned int*)g,
      (__attribute__((address_space(3))) unsigned int*)l, 16, 0, 0);
}

// Wt[4h+g][k] = (k<512 ? kernel[k][g*512+h] : recurrent[k-512][g*512+h]) in bf16.
__global__ void prep_w(const float* __restrict__ Wk, const float* __restrict__ Wr,
                       const float* __restrict__ bias,
                       unsigned short* __restrict__ Wt, float* __restrict__ biasr)
{
  int gid = (blockIdx.x << 8) + threadIdx.x;   // 0 .. 2M-1
  int k   = gid >> 11;
  int col = gid & 2047;
  float v = (k < 512) ? Wk[((size_t)k << 11) + col]
                      : Wr[((size_t)(k - 512) << 11) + col];
  int n = ((col & 511) << 2) | (col >> 9);
  Wt[((size_t)n << 10) + k] = f2bf(v);
  if (gid < 2048) biasr[((gid & 511) << 2) | (gid >> 9)] = bias[gid];
}

// Xbf[t][b][d] = bf16(x[b][t][d])  (time-major for contiguous per-step A source)
__global__ void prep_x(const float* __restrict__ x, unsigned short* __restrict__ Xbf)
{
  int flat = (blockIdx.x << 8) + threadIdx.x;  // 0 .. 4,194,303
  int d8 = flat & 63;
  int b  = (flat >> 6) & 1023;
  int t  = flat >> 16;
  const float* src = x + ((((size_t)b << 6) + t) << 9) + (d8 << 3);
  float4 v0 = *(const float4*)src;
  float4 v1 = *(const float4*)(src + 4);
  uint4 u;
  u.x = f2bf(v0.x) | ((unsigned)f2bf(v0.y) << 16);
  u.y = f2bf(v0.z) | ((unsigned)f2bf(v0.w) << 16);
  u.z = f2bf(v1.x) | ((unsigned)f2bf(v1.y) << 16);
  u.w = f2bf(v1.z) | ((unsigned)f2bf(v1.w) << 16);
  *(uint4*)&Xbf[((((size_t)t << 10) + b) << 9) + (d8 << 3)] = u;
}

__global__ void zero_h(unsigned short* __restrict__ Hb)
{
  int i = (blockIdx.x << 8) + threadIdx.x;     // 0..65535
  *(uint4*)&Hb[(size_t)i << 3] = make_uint4(0u, 0u, 0u, 0u);
}

__global__ __launch_bounds__(512, 2)
void lstm_coop(const unsigned short* __restrict__ Xbf,
               const unsigned short* __restrict__ Wt,
               const float* __restrict__ biasr,
               unsigned short* __restrict__ Hbuf,   // [2][1024][512] bf16
               float* __restrict__ out)             // [1024][64][512] fp32
{
  __shared__ unsigned short Bs[64][1032];                 // 129 KB, pad+8 (16B rows)
  __shared__ __align__(16) unsigned short As[2][128][32]; // 16 KB, 2 sub-chunks
  float (*Zs)[64] = reinterpret_cast<float(*)[64]>(&As[0][0][0]); // epilogue reuse

  const int tid  = threadIdx.x;
  const int lane = tid & 63;
  const int w    = tid >> 6;        // 0..7
  const int llo  = lane & 15;
  const int lhi  = lane >> 4;
  const int wm   = w & 3;           // 4 m-waves of 32 rows
  const int wn   = w >> 2;          // 2 n-waves of 32 cols

  const int bid = blockIdx.x;
  const int mb  = bid & 7;          // same-m blocks land on one XCD (round-robin)
  const int nb  = bid >> 3;         // 0..31
  const int m0  = mb << 7;          // 128-row batch slice
  const int n0  = nb << 6;          // 64 gate-cols
  const int hglob = (nb << 4) + (tid & 15);

  // Load this block's B slice once: rows n0..n0+63, K=1024 (x-part | h-part).
  for (int i = tid; i < 8192; i += 512) {
    int r = i >> 7, kc = (i & 127) << 3;
    *(uint4*)&Bs[r][kc] = *(const uint4*)&Wt[(((size_t)(n0 + r)) << 10) + kc];
  }
  float4 bb = *(const float4*)&biasr[(size_t)hglob << 2];
  float creg[4] = {0.f, 0.f, 0.f, 0.f};

  const int srow = (w << 4) + (lane >> 2);   // staging row 0..127
  const int sseg = (lane & 3) << 3;          // elem offset {0,8,16,24}

  cg::grid_group grid = cg::this_grid();
  __syncthreads();

  for (int t = 0; t < 64; ++t) {
    const unsigned short* Hprev = Hbuf + ((size_t)(t & 1) << 19);
    unsigned short*       Hnext = Hbuf + ((size_t)((t + 1) & 1) << 19);

    facc4 acc00 = {0.f,0.f,0.f,0.f};
    facc4 acc01 = acc00, acc10 = acc00, acc11 = acc00;

    for (int ci = 0; ci < 16; ++ci) {
      const int kb = ci << 6;
#pragma unroll
      for (int s = 0; s < 2; ++s) {
        const int k = kb + (s << 5) + sseg;
        const unsigned short* g = (kb < 512)
            ? Xbf + ((((size_t)t << 10) + (m0 + srow)) << 9) + k
            : Hprev + (((size_t)(m0 + srow)) << 9) + (k - 512);
        gl2lds16(g, &As[s][srow][sseg]);   // dest = wave base + lane*16 (verified)
      }
      __syncthreads();   // drains vmcnt -> As ready
#pragma unroll
      for (int s = 0; s < 2; ++s) {
        bfrag8 a0 = *(const bfrag8*)&As[s][(wm << 5) + llo][lhi << 3];
        bfrag8 a1 = *(const bfrag8*)&As[s][(wm << 5) + 16 + llo][lhi << 3];
        bfrag8 b0 = *(const bfrag8*)&Bs[(wn << 5) + llo][kb + (s << 5) + (lhi << 3)];
        bfrag8 b1 = *(const bfrag8*)&Bs[(wn << 5) + 16 + llo][kb + (s << 5) + (lhi << 3)];
        acc00 = MFMA_B16(a0, b0, acc00);
        acc01 = MFMA_B16(a0, b1, acc01);
        acc10 = MFMA_B16(a1, b0, acc10);
        acc11 = MFMA_B16(a1, b1, acc11);
      }
      __syncthreads();   // before As reuse
    }

    // Epilogue: spill z to Zs (reuses As, 16 KB) in two 64-row halves.
    const int hs = tid & 15;
    const int rw = tid >> 4;       // 0..31
#pragma unroll
    for (int ph = 0; ph < 2; ++ph) {
      if ((wm >> 1) == ph) {
#pragma unroll
        for (int rr = 0; rr < 4; ++rr) {
          int lr = ((wm & 1) << 5) + (lhi << 2) + rr;   // 0..63 within half
          int cb = (wn << 5) + llo;
          Zs[lr][cb]           = acc00[rr];
          Zs[lr][cb + 16]      = acc01[rr];
          Zs[lr + 16][cb]      = acc10[rr];
          Zs[lr + 16][cb + 16] = acc11[rr];
        }
      }
      __syncthreads();
#pragma unroll
      for (int half = 0; half < 2; ++half) {
        int rloc = rw + (half << 5);                    // 0..63
        float4 z = *(const float4*)&Zs[rloc][hs << 2];
        float ig = sigm(z.x + bb.x);
        float fg = sigm(z.y + bb.y);
        float gg = tanh_(z.z + bb.z);
        float og = sigm(z.w + bb.w);
        int ci4 = (ph << 1) + half;                     // fixed per-thread c slot
        float cn = fg * creg[ci4] + ig * gg;
        creg[ci4] = cn;
        float hn = og * tanh_(cn);
        int brow = m0 + (ph << 6) + rloc;
        Hnext[((size_t)brow << 9) + hglob] = f2bf(hn);
        out[((((size_t)brow << 6) + (size_t)t) << 9) + hglob] = hn;
      }
      __syncthreads();
    }

    __threadfence();   // release h writes device-wide (cross-XCD)
    grid.sync();
  }
}

extern "C" void kernel_launch(void* const* d_in, const int* in_sizes, int n_in,
                              void* d_out, int out_size, void* d_ws, size_t ws_size,
                              hipStream_t stream) {
  const float* x    = (const float*)d_in[0];   // [1024][64][512]
  const float* Wk   = (const float*)d_in[1];   // [512][2048]
  const float* Wr   = (const float*)d_in[2];   // [512][2048]
  const float* bias = (const float*)d_in[3];   // [2048]
  float* out = (float*)d_out;

  char* ws = (char*)d_ws;
  // ws: Wt 4MB | biasr 8KB | Xbf 64MB | Hbuf 2MB   (~70 MB)
  unsigned short* Wt    = (unsigned short*)(ws);
  float*          biasr = (float*)(ws + 4194304);
  unsigned short* Xbf   = (unsigned short*)(ws + 4202496);
  unsigned short* Hbuf  = (unsigned short*)(ws + 71311360);

  prep_w<<<dim3(8192), dim3(256), 0, stream>>>(Wk, Wr, bias, Wt, biasr);
  prep_x<<<dim3(16384), dim3(256), 0, stream>>>(x, Xbf);
  zero_h<<<dim3(256), dim3(256), 0, stream>>>(Hbuf);

  const unsigned short* Xc = Xbf;
  const unsigned short* Wc = Wt;
  const float*          bc = biasr;
  unsigned short*       Hc = Hbuf;
  float*                oc = out;
  void* args[5] = { &Xc, &Wc, &bc, &Hc, &oc };
  hipLaunchCooperativeKernel((void*)lstm_coop, dim3(256), dim3(512), args, 0, stream);
}

// Round 3
// 1120.608 us; speedup vs baseline: 4.8300x; 4.8300x over previous
//
#include <hip/hip_runtime.h>
#include <hip/hip_bf16.h>
#include <hip/hip_fp16.h>

// LSTM, T=64. Structure:
//   prep_w : Wx[2048][512], Wh[2048][512] bf16 (gate-interleaved n=4h+g, K-transposed), biasr.
//   prep_x : Xbf[t][b][512] bf16 (time-major).
//   zx_gemm: zx[t][b][2048] = Xbf @ Wx^T, fp16 storage. One parallel GEMM (half the FLOPs,
//            off the sequential critical path).
//   lstm_step x64: z = zx[t] + h_{t-1} @ Wh^T (K=512, bf16 MFMA) + cell epilogue.
//            h ping-pongs between Hbuf[0/1] (no intra-step race), c in Cst fp32.
// LDS staging: global_load_lds width=16 with XOR-swizzled SOURCE permutation
// (phys granule = (seg&8)|((seg^row)&7)) so unpadded frag reads are bank-optimal.

typedef __attribute__((ext_vector_type(8))) short bfrag8;
typedef __attribute__((ext_vector_type(4))) float facc4;

#define MFMA_B16(a, b, c) __builtin_amdgcn_mfma_f32_16x16x32_bf16(a, b, c, 0, 0, 0)

__device__ __forceinline__ unsigned short f2bf(float f) {
  unsigned int u = __float_as_uint(f);
  u += 0x7FFFu + ((u >> 16) & 1u);          // RNE
  return (unsigned short)(u >> 16);
}
__device__ __forceinline__ float sigm(float x)  { return 1.0f / (1.0f + __expf(-x)); }
__device__ __forceinline__ float tanh_(float x) { return 1.0f - 2.0f / (__expf(2.0f * x) + 1.0f); }

__device__ __forceinline__ void gl2lds16(const void* g, void* l) {
  __builtin_amdgcn_global_load_lds(
      (const __attribute__((address_space(1))) unsigned int*)g,
      (__attribute__((address_space(3))) unsigned int*)l, 16, 0, 0);
}

// ushort offset of logical granule (row, seg) in a [64 rows][16 segs] swizzled tile.
__device__ __forceinline__ int foff(int row, int seg) {
  return (row << 7) + ((((seg & 8) | ((seg ^ row) & 7))) << 3);
}

// ---------------- prep kernels ----------------

__global__ void prep_w(const float* __restrict__ Wk, const float* __restrict__ Wr,
                       const float* __restrict__ bias,
                       unsigned short* __restrict__ Wx, unsigned short* __restrict__ Wh,
                       float* __restrict__ biasr)
{
  int gid = (blockIdx.x << 8) + threadIdx.x;   // 0 .. 2M-1
  int k   = gid >> 11;                         // 0..1023
  int col = gid & 2047;                        // original column g*512+h
  float v = (k < 512) ? Wk[((size_t)k << 11) + col]
                      : Wr[((size_t)(k - 512) << 11) + col];
  int n = ((col & 511) << 2) | (col >> 9);     // 4h+g
  if (k < 512) Wx[((size_t)n << 9) + k]         = f2bf(v);
  else         Wh[((size_t)n << 9) + (k - 512)] = f2bf(v);
  if (gid < 2048) biasr[((gid & 511) << 2) | (gid >> 9)] = bias[gid];
}

__global__ void prep_x(const float* __restrict__ x, unsigned short* __restrict__ Xbf)
{
  int flat = (blockIdx.x << 8) + threadIdx.x;  // 0 .. 4,194,303 (granules of 8)
  int d8 = flat & 63;
  int b  = (flat >> 6) & 1023;
  int t  = flat >> 16;
  const float* src = x + ((((size_t)b << 6) + t) << 9) + (d8 << 3);
  float4 v0 = *(const float4*)src;
  float4 v1 = *(const float4*)(src + 4);
  uint4 u;
  u.x = f2bf(v0.x) | ((unsigned)f2bf(v0.y) << 16);
  u.y = f2bf(v0.z) | ((unsigned)f2bf(v0.w) << 16);
  u.z = f2bf(v1.x) | ((unsigned)f2bf(v1.y) << 16);
  u.w = f2bf(v1.z) | ((unsigned)f2bf(v1.w) << 16);
  *(uint4*)&Xbf[((((size_t)t << 10) + b) << 9) + (d8 << 3)] = u;
}

// ---------------- zx precompute GEMM ----------------
// zx[t][b][n] (fp16) = Xbf[t][b][:] . Wx[n][:]   M=65536, N=2048, K=512
__global__ __launch_bounds__(256, 3)
void zx_gemm(const unsigned short* __restrict__ Xbf, const unsigned short* __restrict__ Wx,
             unsigned short* __restrict__ zx)
{
  __shared__ __align__(16) unsigned short As[8192];   // 16 KB, 1024 granules (swizzled)
  __shared__ __align__(16) unsigned short Bs[8192];
  __shared__ float Zs[64][68];

  const int tid  = threadIdx.x;
  const int lane = tid & 63;
  const int w    = tid >> 6;
  const int llo  = lane & 15;
  const int lhi  = lane >> 4;
  const int wm   = (w >> 1) & 1;
  const int wn   = w & 1;

  const int n0 = blockIdx.x << 6;              // 0..2047 step 64
  const int by = blockIdx.y;                   // 0..1023
  const int t  = by >> 4;
  const int b0 = (by & 15) << 6;

  facc4 acc00 = {0.f,0.f,0.f,0.f};
  facc4 acc01 = acc00, acc10 = acc00, acc11 = acc00;

  const int am0 = (wm << 5) + llo;
  const int bn0 = (wn << 5) + llo;

  for (int ci = 0; ci < 4; ++ci) {
    const int kb = ci << 7;
#pragma unroll
    for (int j = 0; j < 4; ++j) {
      int p = (j << 8) + tid;
      int r = p >> 4, ps = p & 15;
      int s = (ps & 8) | ((ps ^ r) & 7);
      gl2lds16(Xbf + ((((size_t)t << 10) + (b0 + r)) << 9) + kb + (s << 3), &As[p << 3]);
      gl2lds16(Wx  + (((size_t)(n0 + r)) << 9) + kb + (s << 3),             &Bs[p << 3]);
    }
    __syncthreads();
#pragma unroll
    for (int kk = 0; kk < 4; ++kk) {
      const int s0 = (kk << 2) + lhi;
      bfrag8 a0 = *(const bfrag8*)&As[foff(am0,      s0)];
      bfrag8 a1 = *(const bfrag8*)&As[foff(am0 + 16, s0)];
      bfrag8 b0 = *(const bfrag8*)&Bs[foff(bn0,      s0)];
      bfrag8 b1 = *(const bfrag8*)&Bs[foff(bn0 + 16, s0)];
      acc00 = MFMA_B16(a0, b0, acc00);
      acc01 = MFMA_B16(a0, b1, acc01);
      acc10 = MFMA_B16(a1, b0, acc10);
      acc11 = MFMA_B16(a1, b1, acc11);
    }
    __syncthreads();
  }

  // spill: C/D layout col=lane&15, row=(lane>>4)*4+reg
#pragma unroll
  for (int rr = 0; rr < 4; ++rr) {
    int rbase = (wm << 5) + (lhi << 2) + rr;
    int cbase = (wn << 5) + llo;
    Zs[rbase][cbase]           = acc00[rr];
    Zs[rbase][cbase + 16]      = acc01[rr];
    Zs[rbase + 16][cbase]      = acc10[rr];
    Zs[rbase + 16][cbase + 16] = acc11[rr];
  }
  __syncthreads();

  const int hs = tid & 15;
  const int rw = tid >> 4;
#pragma unroll
  for (int it = 0; it < 4; ++it) {
    int row = rw + (it << 4);
    float4 z = *(const float4*)&Zs[row][hs << 2];
    ushort4 o;
    o.x = __half_as_ushort(__float2half(z.x));
    o.y = __half_as_ushort(__float2half(z.y));
    o.z = __half_as_ushort(__float2half(z.z));
    o.w = __half_as_ushort(__float2half(z.w));
    *(ushort4*)&zx[((((size_t)t << 10) + (b0 + row)) << 11) + n0 + (hs << 2)] = o;
  }
}

// ---------------- recurrent step ----------------
// z = zx[t] + h_{t-1} @ Wh^T ; gates; c,h update.  M=1024, N=2048, K=512.
__global__ __launch_bounds__(256, 2)
void lstm_step(const unsigned short* __restrict__ Hprev,   // [1024][512] bf16
               unsigned short* __restrict__ Hnext,
               const unsigned short* __restrict__ Wh,      // [2048][512] bf16
               const unsigned short* __restrict__ zxt,     // [1024][2048] fp16 (step slice)
               const float* __restrict__ biasr,
               float* __restrict__ Cst,                    // [1024][512] fp32
               float* __restrict__ outt,                   // out + t*512
               int t0)
{
  __shared__ __align__(16) unsigned short As[8192];
  __shared__ __align__(16) unsigned short Bs[8192];
  __shared__ float Zs[64][68];

  const int tid  = threadIdx.x;
  const int lane = tid & 63;
  const int w    = tid >> 6;
  const int llo  = lane & 15;
  const int lhi  = lane >> 4;
  const int wm   = (w >> 1) & 1;
  const int wn   = w & 1;

  const int n0 = blockIdx.x << 6;
  const int m0 = blockIdx.y << 6;
  const int hs = tid & 15;
  const int rw = tid >> 4;
  const int hglob = (blockIdx.x << 4) + hs;

  // Prefetch epilogue operands (latency hidden under the GEMM).
  float4 bb = *(const float4*)&biasr[(size_t)hglob << 2];
  ushort4 zp[4];
  float   cpre[4];
#pragma unroll
  for (int it = 0; it < 4; ++it) {
    int b = m0 + rw + (it << 4);
    zp[it]   = *(const ushort4*)&zxt[((size_t)b << 11) + n0 + (hs << 2)];
    cpre[it] = t0 ? 0.0f : Cst[((size_t)b << 9) + hglob];
  }

  facc4 acc00 = {0.f,0.f,0.f,0.f};
  facc4 acc01 = acc00, acc10 = acc00, acc11 = acc00;

  const int am0 = (wm << 5) + llo;
  const int bn0 = (wn << 5) + llo;

  if (!t0) {
    for (int ci = 0; ci < 4; ++ci) {
      const int kb = ci << 7;
#pragma unroll
      for (int j = 0; j < 4; ++j) {
        int p = (j << 8) + tid;
        int r = p >> 4, ps = p & 15;
        int s = (ps & 8) | ((ps ^ r) & 7);
        gl2lds16(Hprev + (((size_t)(m0 + r)) << 9) + kb + (s << 3), &As[p << 3]);
        gl2lds16(Wh    + (((size_t)(n0 + r)) << 9) + kb + (s << 3), &Bs[p << 3]);
      }
      __syncthreads();
#pragma unroll
      for (int kk = 0; kk < 4; ++kk) {
        const int s0 = (kk << 2) + lhi;
        bfrag8 a0 = *(const bfrag8*)&As[foff(am0,      s0)];
        bfrag8 a1 = *(const bfrag8*)&As[foff(am0 + 16, s0)];
        bfrag8 b0 = *(const bfrag8*)&Bs[foff(bn0,      s0)];
        bfrag8 b1 = *(const bfrag8*)&Bs[foff(bn0 + 16, s0)];
        acc00 = MFMA_B16(a0, b0, acc00);
        acc01 = MFMA_B16(a0, b1, acc01);
        acc10 = MFMA_B16(a1, b0, acc10);
        acc11 = MFMA_B16(a1, b1, acc11);
      }
      __syncthreads();
    }
  }

#pragma unroll
  for (int rr = 0; rr < 4; ++rr) {
    int rbase = (wm << 5) + (lhi << 2) + rr;
    int cbase = (wn << 5) + llo;
    Zs[rbase][cbase]           = acc00[rr];
    Zs[rbase][cbase + 16]      = acc01[rr];
    Zs[rbase + 16][cbase]      = acc10[rr];
    Zs[rbase + 16][cbase + 16] = acc11[rr];
  }
  __syncthreads();

#pragma unroll
  for (int it = 0; it < 4; ++it) {
    int row = rw + (it << 4);
    int b   = m0 + row;
    float4 z = *(const float4*)&Zs[row][hs << 2];
    float zi = z.x + __half2float(__ushort_as_half(zp[it].x)) + bb.x;
    float zf = z.y + __half2float(__ushort_as_half(zp[it].y)) + bb.y;
    float zg = z.z + __half2float(__ushort_as_half(zp[it].z)) + bb.z;
    float zo = z.w + __half2float(__ushort_as_half(zp[it].w)) + bb.w;
    float ig = sigm(zi);
    float fg = sigm(zf);
    float gg = tanh_(zg);
    float og = sigm(zo);
    float cn = fg * cpre[it] + ig * gg;
    float hn = og * tanh_(cn);
    size_t idx = ((size_t)b << 9) + hglob;
    Cst[idx]  = cn;
    Hnext[idx] = f2bf(hn);
    outt[((size_t)b << 15) + hglob] = hn;
  }
}

extern "C" void kernel_launch(void* const* d_in, const int* in_sizes, int n_in,
                              void* d_out, int out_size, void* d_ws, size_t ws_size,
                              hipStream_t stream) {
  const float* x    = (const float*)d_in[0];   // [1024][64][512]
  const float* Wk   = (const float*)d_in[1];   // [512][2048]
  const float* Wr   = (const float*)d_in[2];   // [512][2048]
  const float* bias = (const float*)d_in[3];   // [2048]
  float* out = (float*)d_out;                  // [1024][64][512]

  char* ws = (char*)d_ws;
  // ws (16B-aligned): Wx 2MiB | Wh 2MiB | biasr 8KB | Hbuf 2MiB | Cst 2MiB | Xbf 64MiB | zx 256MiB
  unsigned short* Wx    = (unsigned short*)(ws);
  unsigned short* Wh    = (unsigned short*)(ws + (2u << 20));
  float*          biasr = (float*)(ws + (4u << 20));
  unsigned short* Hbuf  = (unsigned short*)(ws + (4u << 20) + 8192);
  float*          Cst   = (float*)(ws + (6u << 20) + 8192);
  unsigned short* Xbf   = (unsigned short*)(ws + (8u << 20) + 8192);
  unsigned short* zx    = (unsigned short*)(ws + (72u << 20) + 8192);

  prep_w<<<dim3(8192), dim3(256), 0, stream>>>(Wk, Wr, bias, Wx, Wh, biasr);
  prep_x<<<dim3(16384), dim3(256), 0, stream>>>(x, Xbf);
  zx_gemm<<<dim3(32, 1024), dim3(256), 0, stream>>>(Xbf, Wx, zx);

  const size_t HSZ = (size_t)1024 * 512;       // elems per h buffer
  for (int t = 0; t < 64; ++t) {
    unsigned short* Hprev = Hbuf + (size_t)(t & 1) * HSZ;
    unsigned short* Hnext = Hbuf + (size_t)((t + 1) & 1) * HSZ;
    lstm_step<<<dim3(32, 16), dim3(256), 0, stream>>>(
        Hprev, Hnext, Wh, zx + ((size_t)t << 21), biasr, Cst,
        out + ((size_t)t << 9), (t == 0) ? 1 : 0);
  }
}